// Round 9
// baseline (160.196 us; speedup 1.0000x reference)
//
#include <hip/hip_runtime.h>
#include <hip/hip_bf16.h>
#include <math.h>

#define B_   128
#define LQ_  64
#define LD_  512
#define E_   300
#define K_   11
#define DCH  32     // d-rows per chunk
#define CPB  4      // chunks per block (double-buffered full-chunk pipeline)
#define NBLK 4      // blocks per batch = LD / (DCH*CPB)
#define NGR  2      // 16-row B-frag groups per chunk
#define NT   10     // e-tiles of 32 (300 padded to 320)
#define CSTR 132    // epilogue sims row stride (floats, %32==4 -> 2-way alias)
#define CF   (DCH * E_)  // floats per chunk = 9600 (38400 B, contiguous)

typedef __bf16  bf16x8  __attribute__((ext_vector_type(8)));
typedef float   floatx4 __attribute__((ext_vector_type(4)));

// factorized RBF: kernel k (1..10, mu=0.9..-0.9 step -0.2, sigma=0.1):
//   exp(-50(s-mu_k)^2) = t_k * CK2[k],  t_1 = exp(90s-50s^2), t_{k+1} = t_k*exp(-20s)
__device__ __constant__ float CK2_C[10] =
    {2.576757e-18f, 2.288464e-11f, 3.726653e-06f, 1.110900e-02f, 6.065307e-01f,
     6.065307e-01f, 1.110900e-02f, 3.726653e-06f, 2.288464e-11f, 2.576757e-18f};

__device__ __forceinline__ unsigned int pk2(float x, float y) {
    __hip_bfloat162 h = __float22bfloat162_rn(make_float2(x, y));
    union { __hip_bfloat162 h2; unsigned int u; } c;
    c.h2 = h;
    return c.u;
}

// async global->LDS, 16 B per lane; LDS dest = uniform base + lane*16 (HW rule)
__device__ __forceinline__ void gload16(const float* g, float* l) {
    __builtin_amdgcn_global_load_lds(
        (const __attribute__((address_space(1))) unsigned int*)g,
        (__attribute__((address_space(3))) unsigned int*)l, 16, 0, 0);
}

// Chunk double-buffer; dead after the chunk loop, so epilogue sims alias it.
union __align__(16) ShD {
    float dbuf[2 * CF];     // 76800 B: 2 full 32-row chunks fp32
    float cs[LQ_ * CSTR];   // 33792 B: normalized sims (64q x 128d)
};

// R7 best (138.5 us): block = (batch, 128-row span), 4 chunks of 32 rows,
// whole-chunk double buffer, STAGE(c+1) in flight under chunk-c compute.
// KEPT BYTE-IDENTICAL THIS ROUND (measurement round — see bw_probe below).
__global__ __launch_bounds__(256, 2) void knrm_main(
    const float* __restrict__ Q, const float* __restrict__ D,
    const float* __restrict__ mask_d, float* __restrict__ psum)
{
    const int b = blockIdx.x, blk = blockIdx.y;
    const int tid  = threadIdx.x;
    const int lane = tid & 63;
    const int w    = tid >> 6;      // 0..3, wave's q-slice / stage quarter
    const int quad = lane >> 4;
    const int l15  = lane & 15;

    __shared__ ShD sh;
    __shared__ __align__(16) float md_s[DCH * CPB];   // 128 d-mask values

    const float* gD = D + ((size_t)b * LD_ + blk * DCH * CPB) * E_;  // 128 rows

    // stage chunk c (32 rows = 38400 B contiguous) into dbuf[buf]: wave w
    // copies floats w*2400..+2400 = 9 full 1024-B instrs + one 384-B tail.
#define STAGE(c, buf) do {                                                \
        const float* sB = gD + (size_t)(c) * CF + w * 2400;               \
        float*       dB = &sh.dbuf[(buf) * CF + w * 2400];                \
        _Pragma("unroll")                                                 \
        for (int i = 0; i < 9; ++i)                                       \
            gload16(sB + i * 256 + lane * 4, dB + i * 256);               \
        if (lane < 24) gload16(sB + 2304 + lane * 4, dB + 2304);          \
    } while (0)

    STAGE(0, 0);   // in flight under Q fragment loads + norm

    // ---- Q A-fragments -> registers (fp32 -> bf16), fused row norm ----
    const float tm0 = (quad <= 1) ? 1.f : 0.f;            // tile-9 validity
    const float tm1 = (quad == 0) ? 1.f : 0.f;            // (cols >= 300 masked)
    const float* qp = Q + ((size_t)b * LQ_ + w * 16 + l15) * E_;

    bf16x8 qf[NT];   // 40 VGPRs
    float ssq = 0.f;
#pragma unroll
    for (int t = 0; t < NT; ++t) {
        const int c0 = t * 32 + quad * 8;
        float4 a, c;
        if (t < NT - 1) {
            a = *(const float4*)(qp + c0);
            c = *(const float4*)(qp + c0 + 4);
        } else {   // tile 9: quad0 fully valid, quad1 half, quads 2-3 invalid
            a = *(const float4*)(qp + (quad <= 1 ? c0 : 0));
            c = *(const float4*)(qp + (quad == 0 ? c0 + 4 : 0));
            a.x *= tm0; a.y *= tm0; a.z *= tm0; a.w *= tm0;
            c.x *= tm1; c.y *= tm1; c.z *= tm1; c.w *= tm1;
        }
        ssq += a.x * a.x + a.y * a.y + a.z * a.z + a.w * a.w;
        ssq += c.x * c.x + c.y * c.y + c.z * c.z + c.w * c.w;
        union { uint4 u; bf16x8 v; } qc;
        qc.u = make_uint4(pk2(a.x, a.y), pk2(a.z, a.w),
                          pk2(c.x, c.y), pk2(c.z, c.w));
        qf[t] = qc.v;
    }
    ssq += __shfl_xor(ssq, 16);
    ssq += __shfl_xor(ssq, 32);
    const float qinv = 1.0f / fmaxf(sqrtf(ssq), 1e-12f);   // for q-row w*16+l15

    if (tid < DCH * CPB)
        md_s[tid] = mask_d[(size_t)b * LD_ + blk * DCH * CPB + tid];
    __syncthreads();   // drains STAGE(0) (vmcnt 0) + md_s visible

    // ---- chunk loop: full-chunk prefetch pipeline ----
    floatx4 acc[CPB][NGR];     // 32 VGPRs
    float dinvv[CPB][NGR];
    floatx4 zero4 = {0.f, 0.f, 0.f, 0.f};
#pragma unroll
    for (int c = 0; c < CPB; ++c)
#pragma unroll
        for (int g = 0; g < NGR; ++g) acc[c][g] = zero4;

#pragma unroll
    for (int c = 0; c < CPB; ++c) {
        if (c + 1 < CPB) STAGE(c + 1, (c + 1) & 1);   // full-chunk prefetch

#pragma unroll
        for (int g = 0; g < NGR; ++g) {
            const float* rowp = &sh.dbuf[(c & 1) * CF + (g * 16 + l15) * E_];
            float lssd = 0.f;
#pragma unroll
            for (int t = 0; t < NT; ++t) {
                const int c0 = t * 32 + quad * 8;
                float4 a, cc;
                if (t < NT - 1) {
                    a  = *(const float4*)(rowp + c0);
                    cc = *(const float4*)(rowp + c0 + 4);
                } else {   // tile 9 masking (rows are 300 floats in LDS)
                    a  = *(const float4*)(rowp + (quad <= 1 ? c0 : 0));
                    cc = *(const float4*)(rowp + (quad == 0 ? c0 + 4 : 0));
                    a.x  *= tm0; a.y  *= tm0; a.z  *= tm0; a.w  *= tm0;
                    cc.x *= tm1; cc.y *= tm1; cc.z *= tm1; cc.w *= tm1;
                }
                lssd += a.x * a.x + a.y * a.y + a.z * a.z + a.w * a.w;
                lssd += cc.x * cc.x + cc.y * cc.y + cc.z * cc.z + cc.w * cc.w;

                union { uint4 u; bf16x8 v; } bc;
                bc.u = make_uint4(pk2(a.x, a.y), pk2(a.z, a.w),
                                  pk2(cc.x, cc.y), pk2(cc.z, cc.w));
                acc[c][g] = __builtin_amdgcn_mfma_f32_16x16x32_bf16(
                                qf[t], bc.v, acc[c][g], 0, 0, 0);
            }
            lssd += __shfl_xor(lssd, 16);
            lssd += __shfl_xor(lssd, 32);
            dinvv[c][g] = 1.0f / fmaxf(sqrtf(lssd), 1e-12f);
        }

        if (c + 1 < CPB) {
            asm volatile("s_waitcnt vmcnt(0)" ::: "memory");
            __builtin_amdgcn_s_barrier();
            asm volatile("" ::: "memory");
        }
    }

    // ---- epilogue: normalized sims -> LDS (aliases dbuf), repartition, pool ----
    __syncthreads();   // all dbuf reads done before aliasing as cs
    float qr[4];
#pragma unroll
    for (int r = 0; r < 4; ++r) qr[r] = __shfl(qinv, quad * 4 + r);
#pragma unroll
    for (int c = 0; c < CPB; ++c)
#pragma unroll
        for (int g = 0; g < NGR; ++g)
#pragma unroll
            for (int r = 0; r < 4; ++r) {
                const int q = w * 16 + quad * 4 + r;
                sh.cs[q * CSTR + c * 32 + g * 16 + l15] =
                    acc[c][g][r] * qr[r] * dinvv[c][g];
            }
    __syncthreads();

    const int pq = tid >> 2, pd = tid & 3;
    float kacc[K_];
#pragma unroll
    for (int k = 0; k < K_; ++k) kacc[k] = 0.f;

#pragma unroll
    for (int h = 0; h < 2; ++h) {
        union { float4 v[4]; float f[16]; } sb, mb;
#pragma unroll
        for (int i = 0; i < 4; ++i) {
            sb.v[i] = *(const float4*)&sh.cs[pq * CSTR + pd * 32 + h * 16 + i * 4];
            mb.v[i] = *(const float4*)&md_s[pd * 32 + h * 16 + i * 4];
        }
#pragma unroll
        for (int j = 0; j < 16; ++j) {
            float s = sb.f[j];
            float m = mb.f[j];
            float df0 = s - 1.0f;
            kacc[0] = fmaf(__expf(df0 * df0 * -500000.0f), m, kacc[0]);
            float t1 = __expf(fmaf(-50.0f * s, s, 90.0f * s));  // arg <= 40.5
            float r  = __expf(-20.0f * s);
            float t  = t1 * m;
#pragma unroll
            for (int k = 1; k < K_; ++k) {
                kacc[k] = fmaf(t, CK2_C[k - 1], kacc[k]);
                t *= r;
            }
        }
    }
#pragma unroll
    for (int msk = 1; msk <= 2; msk <<= 1)
#pragma unroll
        for (int k = 0; k < K_; ++k) kacc[k] += __shfl_xor(kacc[k], msk);

    if (pd == 0) {
        const size_t base = (((size_t)b * LQ_ + pq) * NBLK + blk) * K_;
#pragma unroll
        for (int k = 0; k < K_; ++k) psum[base + k] = kacc[k];
    }
#undef STAGE
}

// Combine block partials, log-pool, dense + tanh. One wave per batch.
__global__ __launch_bounds__(64) void knrm_final(
    const float* __restrict__ psum, const float* __restrict__ mask_q,
    const float* __restrict__ dw, const float* __restrict__ db,
    float* __restrict__ out)
{
    const int b = blockIdx.x;
    const int q = threadIdx.x;  // 0..63

    const float* pp = psum + ((size_t)b * LQ_ + q) * (NBLK * K_);
    union { float4 v[NBLK * K_ / 4]; float f[NBLK * K_]; } buf;  // 44 floats
#pragma unroll
    for (int i = 0; i < NBLK * K_ / 4; ++i)
        buf.v[i] = *(const float4*)(pp + i * 4);

    float t = 0.0f;
#pragma unroll
    for (int k = 0; k < K_; ++k) {
        float p = buf.f[k] + buf.f[K_ + k] + buf.f[2 * K_ + k] + buf.f[3 * K_ + k];
        p = fmaxf(p, 1e-10f);
        t += logf(p) * dw[k];
    }
    t *= 0.01f * mask_q[(size_t)b * LQ_ + q];

#pragma unroll
    for (int m = 32; m >= 1; m >>= 1) t += __shfl_xor(t, m);
    if (q == 0) out[b] = tanhf(t + db[0]);
}

// MEASUREMENT PROBE (this round only): pure cold-stream read of the first
// ~78.6 MB of the workspace (same byte count as D; fill-written EARLY in the
// iteration -> evicted from L3 by the fill's own 307-MB tail -> cold read).
// Runs AFTER knrm_final so it cannot warm anything main reads. asm sink keeps
// the loads live (no stores, no output effect). dur_us delta vs R7's 138.5
// measures the in-situ achievable cold-read BW:
//   <=18 us => >=4.4 TB/s => main's 2.3 TB/s is kernel-fault, keep optimizing
//   >=28 us => <=2.8 TB/s => main ~44 us is at the in-situ floor => roofline
__global__ __launch_bounds__(256) void bw_probe(
    const float4* __restrict__ w, int n4)
{
    float ax = 0.f, ay = 0.f, az = 0.f, aw = 0.f;
    const int stride = gridDim.x * blockDim.x;
    for (int i = blockIdx.x * blockDim.x + threadIdx.x; i < n4; i += stride) {
        float4 v = w[i];
        ax += v.x; ay += v.y; az += v.z; aw += v.w;
    }
    asm volatile("" :: "v"(ax), "v"(ay), "v"(az), "v"(aw));
}

extern "C" void kernel_launch(void* const* d_in, const int* in_sizes, int n_in,
                              void* d_out, int out_size, void* d_ws, size_t ws_size,
                              hipStream_t stream) {
    const float* Q   = (const float*)d_in[0];  // [B, LQ, E]
    const float* D   = (const float*)d_in[1];  // [B, LD, E]
    const float* mq  = (const float*)d_in[2];  // [B, LQ]
    const float* md  = (const float*)d_in[3];  // [B, LD]
    const float* dw  = (const float*)d_in[4];  // [1, K]
    const float* db  = (const float*)d_in[5];  // [1]
    float* out  = (float*)d_out;               // [B, 1]
    float* psum = (float*)d_ws;                // [B][LQ][4][K] = 1.44 MB

    dim3 grid(B_, NBLK);  // linear id = b + 128*blk -> XCD = b%8
    knrm_main<<<grid, 256, 0, stream>>>(Q, D, md, psum);
    knrm_final<<<B_, 64, 0, stream>>>(psum, mq, dw, db, out);

    // cold-stream BW probe over the workspace head (D-sized span, capped by ws)
    size_t span4 = (size_t)B_ * LD_ * E_ / 4;              // 4,915,200 float4
    if (span4 * 16 > ws_size) span4 = ws_size / 16;
    bw_probe<<<2048, 256, 0, stream>>>((const float4*)d_ws, (int)span4);
}

// Round 10
// 137.524 us; speedup vs baseline: 1.1649x; 1.1649x over previous
//
#include <hip/hip_runtime.h>
#include <hip/hip_bf16.h>
#include <math.h>

#define B_   128
#define LQ_  64
#define LD_  512
#define E_   300
#define K_   11
#define NG8  8      // 16-row groups per block (block owns 128 d-rows)
#define NBUF 4      // LDS group buffers (4-deep rotating pipeline)
#define NBLK 4      // blocks per batch = LD / 128
#define NT   10     // e-tiles of 32 (300 padded to 320)
#define CSTR 132    // epilogue sims row stride (floats, %32==4 -> 2-way alias)
#define GFLT (16 * E_)   // floats per 16-row group = 4800 (19200 B, contiguous)

typedef __bf16  bf16x8  __attribute__((ext_vector_type(8)));
typedef float   floatx4 __attribute__((ext_vector_type(4)));

// factorized RBF: kernel k (1..10, mu=0.9..-0.9 step -0.2, sigma=0.1):
//   exp(-50(s-mu_k)^2) = t_k * CK2[k],  t_1 = exp(90s-50s^2), t_{k+1} = t_k*exp(-20s)
__device__ __constant__ float CK2_C[10] =
    {2.576757e-18f, 2.288464e-11f, 3.726653e-06f, 1.110900e-02f, 6.065307e-01f,
     6.065307e-01f, 1.110900e-02f, 3.726653e-06f, 2.288464e-11f, 2.576757e-18f};

__device__ __forceinline__ unsigned int pk2(float x, float y) {
    __hip_bfloat162 h = __float22bfloat162_rn(make_float2(x, y));
    union { __hip_bfloat162 h2; unsigned int u; } c;
    c.h2 = h;
    return c.u;
}

// async global->LDS, 16 B per lane; LDS dest = uniform base + lane*16 (HW rule)
__device__ __forceinline__ void gload16(const float* g, float* l) {
    __builtin_amdgcn_global_load_lds(
        (const __attribute__((address_space(1))) unsigned int*)g,
        (__attribute__((address_space(3))) unsigned int*)l, 16, 0, 0);
}

// 4-buffer group pipeline; dead after the loop, so epilogue sims alias it.
union __align__(16) ShD {
    float dbuf[NBUF * GFLT];  // 76800 B: 4 x 16-row groups fp32
    float cs[LQ_ * CSTR];     // 33792 B: normalized sims (64q x 128d)
};

// R9 probe: in-situ cold-stream ceiling = 3.6 TB/s (78.6 MB in 21.7 us,
// free-running reader). Main at ~2.3 TB/s -> partial kernel-fault. Every
// prior structure drained vmcnt to 0 at each chunk boundary (R7) or kept
// only 1 group in flight (R5) -> the block's load queue goes cold at every
// sync. This version is T3/T4 proper: 4 rotating LDS buffers, prologue
// issues groups 0-2, steady loop = { vmcnt(10): oldest group landed while
// TWO groups (38.4 KB) stay in flight ACROSS the barrier; s_barrier (no
// drain); compute(g); STAGE(g+3) }. vmcnt bookkeeping is exact: the loop
// body has no other VMEM, and a vmcnt(0) before the prologue clears the
// Q-phase residue. Buffer reuse safe: STAGE(g+3) overwrites buf[(g-1)&3],
// already protected by the g-top barrier (all waves finished compute(g-1)).
__global__ __launch_bounds__(256, 2) void knrm_main(
    const float* __restrict__ Q, const float* __restrict__ D,
    const float* __restrict__ mask_d, float* __restrict__ psum)
{
    const int b = blockIdx.x, blk = blockIdx.y;
    const int tid  = threadIdx.x;
    const int lane = tid & 63;
    const int w    = tid >> 6;      // 0..3, wave's q-slice / stage quarter
    const int quad = lane >> 4;
    const int l15  = lane & 15;

    __shared__ ShD sh;
    __shared__ __align__(16) float md_s[16 * NG8];   // 128 d-mask values

    const float* gD = D + ((size_t)b * LD_ + blk * 16 * NG8) * E_;  // 128 rows

    // stage 16-row group g into dbuf[g&3]: wave w copies floats w*1200..+1200
    // (4800 B contiguous) = 4 full 1024-B instrs + one 704-B (44-lane) tail
    // = exactly 5 vmcnt events per wave per group.
#define STAGE(g) do {                                                     \
        const float* sB = gD + (size_t)(g) * GFLT + w * 1200;             \
        float*       dB = &sh.dbuf[((g) & 3) * GFLT + w * 1200];          \
        gload16(sB +       lane * 4, dB);                                 \
        gload16(sB + 256 + lane * 4, dB + 256);                           \
        gload16(sB + 512 + lane * 4, dB + 512);                           \
        gload16(sB + 768 + lane * 4, dB + 768);                           \
        if (lane < 44) gload16(sB + 1024 + lane * 4, dB + 1024);          \
    } while (0)

    // ---- Q A-fragments -> registers (fp32 -> bf16), fused row norm ----
    // Lane (l15,quad) holds q-row w*16+l15, cols t*32+quad*8..+8 (10 tiles).
    const float tm0 = (quad <= 1) ? 1.f : 0.f;            // tile-9 validity
    const float tm1 = (quad == 0) ? 1.f : 0.f;            // (cols >= 300 masked)
    const float* qp = Q + ((size_t)b * LQ_ + w * 16 + l15) * E_;

    bf16x8 qf[NT];   // 40 VGPRs
    float ssq = 0.f;
#pragma unroll
    for (int t = 0; t < NT; ++t) {
        const int c0 = t * 32 + quad * 8;
        float4 a, c;
        if (t < NT - 1) {
            a = *(const float4*)(qp + c0);
            c = *(const float4*)(qp + c0 + 4);
        } else {   // tile 9: quad0 fully valid, quad1 half, quads 2-3 invalid
            a = *(const float4*)(qp + (quad <= 1 ? c0 : 0));
            c = *(const float4*)(qp + (quad == 0 ? c0 + 4 : 0));
            a.x *= tm0; a.y *= tm0; a.z *= tm0; a.w *= tm0;
            c.x *= tm1; c.y *= tm1; c.z *= tm1; c.w *= tm1;
        }
        ssq += a.x * a.x + a.y * a.y + a.z * a.z + a.w * a.w;
        ssq += c.x * c.x + c.y * c.y + c.z * c.z + c.w * c.w;
        union { uint4 u; bf16x8 v; } qc;
        qc.u = make_uint4(pk2(a.x, a.y), pk2(a.z, a.w),
                          pk2(c.x, c.y), pk2(c.z, c.w));
        qf[t] = qc.v;
    }
    ssq += __shfl_xor(ssq, 16);
    ssq += __shfl_xor(ssq, 32);
    const float qinv = 1.0f / fmaxf(sqrtf(ssq), 1e-12f);   // for q-row w*16+l15

    if (tid < 16 * NG8)
        md_s[tid] = mask_d[(size_t)b * LD_ + blk * 16 * NG8 + tid];

    // clear residual Q/mask vmcnt so the pipeline's counting is exact
    asm volatile("s_waitcnt vmcnt(0)" ::: "memory");

    // ---- prologue: 3 groups in flight (15 vmcnt events/wave) ----
    STAGE(0); STAGE(1); STAGE(2);

    // ---- group loop: counted-vmcnt pipeline, NEVER drained in-loop ----
    // B-frag lane (l15,quad): group row l15 (LDS stride 300 words = 12 mod 32
    // -> 2-way banks, free), cols t*32+quad*8..+8.
    floatx4 acc[NG8];          // 32 VGPRs
    float dinvv[NG8];
    floatx4 zero4 = {0.f, 0.f, 0.f, 0.f};
#pragma unroll
    for (int g = 0; g < NG8; ++g) acc[g] = zero4;

#pragma unroll
    for (int g = 0; g < NG8; ++g) {
        // wait for group g (oldest 5 loads) while later groups stay in flight:
        // outstanding before wait: g<=5 -> 15, g==6 -> 10, g==7 -> 5.
        if (g <= 5)      asm volatile("s_waitcnt vmcnt(10)" ::: "memory");
        else if (g == 6) asm volatile("s_waitcnt vmcnt(5)"  ::: "memory");
        else             asm volatile("s_waitcnt vmcnt(0)"  ::: "memory");
        __builtin_amdgcn_s_barrier();   // all waves' stage(g) landed; also
        asm volatile("" ::: "memory");  // fences reuse of buf[(g-1)&3]

        const float* rowp = &sh.dbuf[(g & 3) * GFLT + l15 * E_];
        float lssd = 0.f;
#pragma unroll
        for (int t = 0; t < NT; ++t) {
            const int c0 = t * 32 + quad * 8;
            float4 a, cc;
            if (t < NT - 1) {
                a  = *(const float4*)(rowp + c0);
                cc = *(const float4*)(rowp + c0 + 4);
            } else {   // tile 9 masking (rows are 300 floats in LDS)
                a  = *(const float4*)(rowp + (quad <= 1 ? c0 : 0));
                cc = *(const float4*)(rowp + (quad == 0 ? c0 + 4 : 0));
                a.x  *= tm0; a.y  *= tm0; a.z  *= tm0; a.w  *= tm0;
                cc.x *= tm1; cc.y *= tm1; cc.z *= tm1; cc.w *= tm1;
            }
            lssd += a.x * a.x + a.y * a.y + a.z * a.z + a.w * a.w;
            lssd += cc.x * cc.x + cc.y * cc.y + cc.z * cc.z + cc.w * cc.w;

            union { uint4 u; bf16x8 v; } bc;
            bc.u = make_uint4(pk2(a.x, a.y), pk2(a.z, a.w),
                              pk2(cc.x, cc.y), pk2(cc.z, cc.w));
            acc[g] = __builtin_amdgcn_mfma_f32_16x16x32_bf16(
                         qf[t], bc.v, acc[g], 0, 0, 0);
        }
        // d inv-norm: 4 quads of same l15 covered disjoint col ranges
        lssd += __shfl_xor(lssd, 16);
        lssd += __shfl_xor(lssd, 32);
        dinvv[g] = 1.0f / fmaxf(sqrtf(lssd), 1e-12f);

        if (g + 3 < NG8) STAGE(g + 3);   // refill: back to 15 outstanding
    }

    // ---- epilogue: normalized sims -> LDS (aliases dbuf), repartition, pool ----
    // Lane holds acc[g][r] = sim(q = w*16+quad*4+r, d = g*16+l15).
    __syncthreads();   // all dbuf reads done before aliasing as cs
    float qr[4];
#pragma unroll
    for (int r = 0; r < 4; ++r) qr[r] = __shfl(qinv, quad * 4 + r);
#pragma unroll
    for (int g = 0; g < NG8; ++g)
#pragma unroll
        for (int r = 0; r < 4; ++r) {
            const int q = w * 16 + quad * 4 + r;
            sh.cs[q * CSTR + g * 16 + l15] = acc[g][r] * qr[r] * dinvv[g];
        }
    __syncthreads();

    // q-row x 32-d slice per thread (4 threads cover 128 d-cols), two 16-col
    // halves; only 11 kacc regs live (round-3 spill lesson)
    const int pq = tid >> 2, pd = tid & 3;
    float kacc[K_];
#pragma unroll
    for (int k = 0; k < K_; ++k) kacc[k] = 0.f;

#pragma unroll
    for (int h = 0; h < 2; ++h) {
        union { float4 v[4]; float f[16]; } sb, mb;
#pragma unroll
        for (int i = 0; i < 4; ++i) {
            sb.v[i] = *(const float4*)&sh.cs[pq * CSTR + pd * 32 + h * 16 + i * 4];
            mb.v[i] = *(const float4*)&md_s[pd * 32 + h * 16 + i * 4];
        }
#pragma unroll
        for (int j = 0; j < 16; ++j) {
            float s = sb.f[j];
            float m = mb.f[j];
            float df0 = s - 1.0f;
            kacc[0] = fmaf(__expf(df0 * df0 * -500000.0f), m, kacc[0]);
            float t1 = __expf(fmaf(-50.0f * s, s, 90.0f * s));  // arg <= 40.5
            float r  = __expf(-20.0f * s);
            float t  = t1 * m;
#pragma unroll
            for (int k = 1; k < K_; ++k) {
                kacc[k] = fmaf(t, CK2_C[k - 1], kacc[k]);
                t *= r;
            }
        }
    }
#pragma unroll
    for (int msk = 1; msk <= 2; msk <<= 1)
#pragma unroll
        for (int k = 0; k < K_; ++k) kacc[k] += __shfl_xor(kacc[k], msk);

    if (pd == 0) {
        // layout [b][q][blk][k] -> final kernel reads 44 contiguous floats per q
        const size_t base = (((size_t)b * LQ_ + pq) * NBLK + blk) * K_;
#pragma unroll
        for (int k = 0; k < K_; ++k) psum[base + k] = kacc[k];
    }
#undef STAGE
}

// Combine block partials, log-pool, dense + tanh. One wave per batch.
__global__ __launch_bounds__(64) void knrm_final(
    const float* __restrict__ psum, const float* __restrict__ mask_q,
    const float* __restrict__ dw, const float* __restrict__ db,
    float* __restrict__ out)
{
    const int b = blockIdx.x;
    const int q = threadIdx.x;  // 0..63

    const float* pp = psum + ((size_t)b * LQ_ + q) * (NBLK * K_);
    union { float4 v[NBLK * K_ / 4]; float f[NBLK * K_]; } buf;  // 44 floats
#pragma unroll
    for (int i = 0; i < NBLK * K_ / 4; ++i)
        buf.v[i] = *(const float4*)(pp + i * 4);

    float t = 0.0f;
#pragma unroll
    for (int k = 0; k < K_; ++k) {
        float p = buf.f[k] + buf.f[K_ + k] + buf.f[2 * K_ + k] + buf.f[3 * K_ + k];
        p = fmaxf(p, 1e-10f);
        t += logf(p) * dw[k];
    }
    t *= 0.01f * mask_q[(size_t)b * LQ_ + q];

#pragma unroll
    for (int m = 32; m >= 1; m >>= 1) t += __shfl_xor(t, m);
    if (q == 0) out[b] = tanhf(t + db[0]);
}

extern "C" void kernel_launch(void* const* d_in, const int* in_sizes, int n_in,
                              void* d_out, int out_size, void* d_ws, size_t ws_size,
                              hipStream_t stream) {
    const float* Q   = (const float*)d_in[0];  // [B, LQ, E]
    const float* D   = (const float*)d_in[1];  // [B, LD, E]
    const float* mq  = (const float*)d_in[2];  // [B, LQ]
    const float* md  = (const float*)d_in[3];  // [B, LD]
    const float* dw  = (const float*)d_in[4];  // [1, K]
    const float* db  = (const float*)d_in[5];  // [1]
    float* out  = (float*)d_out;               // [B, 1]
    float* psum = (float*)d_ws;                // [B][LQ][4][K] = 1.44 MB

    dim3 grid(B_, NBLK);  // linear id = b + 128*blk -> XCD = b%8
    knrm_main<<<grid, 256, 0, stream>>>(Q, D, md, psum);
    knrm_final<<<B_, 64, 0, stream>>>(psum, mq, dw, db, out);
}